// Round 6
// baseline (192.051 us; speedup 1.0000x reference)
//
#include <hip/hip_runtime.h>

#define N 8192
#define DIN 64
#define DOUT 128
#define KNN 16
#define MSAMP 2048         /* presample columns, stride 4 */
#define NBX 16             /* j-split in main scan (512 j per region) */
#define NST 8              /* stages per block: NST*64 = 512 j */
#define CAND_R 64          /* slots per (row, bx) region == wave width */
#define CAND_C (NBX * CAND_R)   /* 1024 per row */
#define EPS 1.0f           /* candidate-gate margin (passed r8-r11) */
#define DELTA_Q 64         /* verify-gate margin: 0.5 in dist units */
#define VCAP 128           /* verify-list capacity (expect ~45, >10 sigma) */

typedef unsigned long long u64;
typedef __attribute__((ext_vector_type(8))) short bf16x8;
typedef __attribute__((ext_vector_type(4))) float floatx4;

__device__ __forceinline__ unsigned mono(float f) {
    unsigned u = __float_as_uint(f);
    return (u & 0x80000000u) ? ~u : (u | 0x80000000u);
}
__device__ __forceinline__ unsigned short f2bf(float f) {   // RNE float->bf16
    unsigned u = __float_as_uint(f);
    return (unsigned short)((u + 0x7FFFu + ((u >> 16) & 1u)) >> 16);
}
__device__ __forceinline__ unsigned qdist(float dist) {     // round-up quant
    int q = (int)(dist * 128.0f) + 2;
    q = max(q, 0); return (unsigned)min(q, 65535);
}

// K1: fused pre.  4 rows/block -> 2048 blocks = 8 blocks/CU (was 2: grid-
// limited at 25% occupancy).  Also emits Xs: dense copy of sampled rows
// (j = 4*scol) so k_pretau's A-gathers read full L2 lines.  Per-output FMA
// chains identical to R5 -> U,V,sq,Xh bit-identical.
__global__ __launch_bounds__(256, 8) void k_pre(const float* __restrict__ x,
                                                const float* __restrict__ W1,
                                                const float* __restrict__ b1,
                                                float* __restrict__ sq,
                                                float* __restrict__ sqs,
                                                unsigned short* __restrict__ Xh,
                                                unsigned short* __restrict__ Xs,
                                                float* __restrict__ U,
                                                float* __restrict__ V) {
    __shared__ float xs[4][DIN];
    int t = threadIdx.x;
    int r0 = blockIdx.x * 4;
    if (t < 64) {
        float4 xv = ((const float4*)x)[(size_t)r0 * (DIN / 4) + t];
        ((float4*)xs)[t] = xv;
        ushort4 h4;
        h4.x = f2bf(xv.x); h4.y = f2bf(xv.y);
        h4.z = f2bf(xv.z); h4.w = f2bf(xv.w);
        *(ushort4*)&Xh[r0 * DIN + t * 4] = h4;
        if (t < 16)                                  // row r0 is the sampled one
            *(ushort4*)&Xs[(r0 >> 2) * DIN + t * 4] = h4;
    }
    __syncthreads();
    if (t < 4) {
        const float4* xr = (const float4*)xs[t];
        float s0 = 0.f, s1 = 0.f, s2 = 0.f, s3 = 0.f;
#pragma unroll
        for (int q = 0; q < DIN / 4; ++q) {
            float4 a = xr[q];
            s0 = fmaf(a.x, a.x, s0); s1 = fmaf(a.y, a.y, s1);
            s2 = fmaf(a.z, a.z, s2); s3 = fmaf(a.w, a.w, s3);
        }
        float sv = (s0 + s1) + (s2 + s3);
        sq[r0 + t] = sv;
        if (t == 0) sqs[r0 >> 2] = sv;               // sampled rows j = 4*scol
    }
    int o = t & 127, g = t >> 7;                     // g in {0,1}: rows g*2+u
    float aU[2], aV[2];
#pragma unroll
    for (int u = 0; u < 2; ++u) { aU[u] = 0.f; aV[u] = 0.f; }
    for (int kk = 0; kk < DIN; ++kk) {
        float whi = W1[kk * DOUT + o];
        float wlo = W1[(DIN + kk) * DOUT + o];
        float wd = whi - wlo;
#pragma unroll
        for (int u = 0; u < 2; ++u) {
            float xvv = xs[g * 2 + u][kk];
            aU[u] = fmaf(xvv, wd, aU[u]);
            aV[u] = fmaf(xvv, wlo, aV[u]);
        }
    }
    float bb = b1[o];
#pragma unroll
    for (int u = 0; u < 2; ++u) {
        int r = r0 + g * 2 + u;
        U[(size_t)r * DOUT + o] = aU[u] + bb;
        V[(size_t)r * DOUT + o] = aV[u];
    }
}

// K2: fused presample + tau.  8 i-rows/block (1024 blocks), 32 KB LDS,
// lb(512,6) -> 3 blocks/CU = 24 waves (was 2 blocks/16 waves).  Each wave
// radix-selects ONE row (was 2: halved serial ballot chain).  A-fragments
// gathered from dense Xs (full 2 KB L2-line regions, was 1/4-dense Xh
// stride-4 rows).  MFMA B-operand duplicates rows m>=8; their qls stores
// are guarded off.  Same q multiset per row -> tau bit-identical.
__global__ __launch_bounds__(512, 6) void k_pretau(const unsigned short* __restrict__ Xh,
                                                   const unsigned short* __restrict__ Xs,
                                                   const float* __restrict__ sq,
                                                   const float* __restrict__ sqs,
                                                   float* __restrict__ tauf) {
    __shared__ __align__(16) unsigned short qls[8 * MSAMP];   // 32 KB
    int tid = threadIdx.x, w = tid >> 6, l = tid & 63;
    int m = l & 15, quad = l >> 4, ko = quad * 8;
    int rt = blockIdx.x;
    int irow = rt * 8 + (m & 7);                     // rows duplicated for m>=8
    size_t arow = (size_t)irow * DIN;
    bf16x8 iH0 = *(const bf16x8*)(Xh + arow + ko);   // i-row frag (B)
    bf16x8 iH1 = *(const bf16x8*)(Xh + arow + 32 + ko);
    float si = sq[irow];
    int swz = (m & 7) << 4;
    for (int it = 0; it < 16; ++it) {
        int s16 = w * 256 + it * 16;                 // scol tile base
        const unsigned short* sp = Xs + (size_t)(s16 + m) * DIN;  // dense rows
        bf16x8 sH0 = *(const bf16x8*)(sp + ko);      // sampled (A)
        bf16x8 sH1 = *(const bf16x8*)(sp + 32 + ko);
        floatx4 acc = {0.f, 0.f, 0.f, 0.f};
        acc = __builtin_amdgcn_mfma_f32_16x16x32_bf16(sH0, iH0, acc, 0, 0, 0);
        acc = __builtin_amdgcn_mfma_f32_16x16x32_bf16(sH1, iH1, acc, 0, 0, 0);
        int sc0 = s16 + quad * 4;                    // 4 consecutive scols
        float4 sj = *(const float4*)(sqs + sc0);
        unsigned q0 = qdist(fmaf(-2.0f, acc[0], si + sj.x));
        unsigned q1 = qdist(fmaf(-2.0f, acc[1], si + sj.y));
        unsigned q2 = qdist(fmaf(-2.0f, acc[2], si + sj.z));
        unsigned q3 = qdist(fmaf(-2.0f, acc[3], si + sj.w));
        if (m < 8) {                                 // valid i-rows only
            u64 pk = (u64)q0 | ((u64)q1 << 16) | ((u64)q2 << 32) | ((u64)q3 << 48);
            *(u64*)&qls[m * MSAMP + (sc0 ^ swz)] = pk;   // multiset-preserving
        }
    }
    __syncthreads();
    // wave w radix-selects row w of the tile.
    unsigned v[MSAMP / 64];
#pragma unroll
    for (int u = 0; u < MSAMP / 64; ++u)
        v[u] = qls[w * MSAMP + l + 64 * u];
    unsigned p = 0;                                  // invariant: #{q < p} < 16
#pragma unroll
    for (int b = 15; b >= 0; --b) {
        unsigned c16 = p | (1u << b);
        int cnt = 0;
#pragma unroll
        for (int u = 0; u < MSAMP / 64; ++u)
            cnt += __popcll(__ballot(v[u] < c16));
        if (cnt < 16) p = c16;                       // wave-uniform
    }
    if (l == 0) tauf[rt * 8 + w] = (float)p * (1.0f / 128.0f);
}

// K3: MFMA main scan (R4 geometry: NBX=16, 8 blocks/CU).
__global__ __launch_bounds__(256, 8) void k_main(const unsigned short* __restrict__ Xh,
                                                 const float* __restrict__ sq,
                                                 const float* __restrict__ tauf,
                                                 unsigned* __restrict__ cand,
                                                 unsigned* __restrict__ cntpart) {
    __shared__ __align__(16) short ldsH[64 * 72];
    int tid = threadIdx.x, w = tid >> 6, l = tid & 63;
    int m = l & 15, ko = (l >> 4) * 8;
    int bx = blockIdx.x;
    int rt = blockIdx.y * 4 + w;
    size_t arow = (size_t)(rt * 16 + m) * DIN;
    bf16x8 aH0 = *(const bf16x8*)(Xh + arow + ko);
    bf16x8 aH1 = *(const bf16x8*)(Xh + arow + 32 + ko);
    int rg[4]; float T[4]; float si[4]; int rowcnt[4];
#pragma unroll
    for (int reg = 0; reg < 4; ++reg) {
        rg[reg] = rt * 16 + (l >> 4) * 4 + reg;
        si[reg] = sq[rg[reg]];
        T[reg] = tauf[rg[reg]] + EPS - si[reg];
        rowcnt[reg] = 0;
    }
    int qs = l & 48;
    unsigned lmask = (1u << (l & 15)) - 1u;
    int srw = tid >> 3, scol8 = (tid & 7) * 8;

    for (int st = 0; st < NST; ++st) {
        int jbase = bx * (NST * 64) + st * 64;
        __syncthreads();
        *(bf16x8*)&ldsH[srw * 72 + scol8] =
            *(const bf16x8*)(Xh + (size_t)(jbase + srw) * DIN + scol8);
        *(bf16x8*)&ldsH[(srw + 32) * 72 + scol8] =
            *(const bf16x8*)(Xh + (size_t)(jbase + srw + 32) * DIN + scol8);
        __syncthreads();
#pragma unroll
        for (int it = 0; it < 4; ++it) {
            int br = it * 16 + m;
            bf16x8 bH0 = *(const bf16x8*)&ldsH[br * 72 + ko];
            bf16x8 bH1 = *(const bf16x8*)&ldsH[br * 72 + 32 + ko];
            floatx4 acc = {0.f, 0.f, 0.f, 0.f};
            acc = __builtin_amdgcn_mfma_f32_16x16x32_bf16(aH0, bH0, acc, 0, 0, 0);
            acc = __builtin_amdgcn_mfma_f32_16x16x32_bf16(aH1, bH1, acc, 0, 0, 0);
            int jcol = jbase + it * 16 + m;
            float sqj = sq[jcol];
#pragma unroll
            for (int reg = 0; reg < 4; ++reg) {
                float tv = fmaf(-2.0f, acc[reg], sqj);   // dist - si
                bool pass = tv <= T[reg];
                u64 bal = __ballot(pass);
                if (bal) {                               // skip empty
                    unsigned m16 = (unsigned)((bal >> qs) & 0xFFFFull);
                    if (pass) {
                        int slot = rowcnt[reg] + __popc(m16 & lmask);
                        if (slot < CAND_R)
                            cand[(size_t)rg[reg] * CAND_C + bx * CAND_R + slot] =
                                (qdist(tv + si[reg]) << 16) | (unsigned)jcol;
                    }
                    rowcnt[reg] += __popc(m16);
                }
            }
        }
    }
    if ((l & 15) == 0) {
#pragma unroll
        for (int reg = 0; reg < 4; ++reg)
            cntpart[rg[reg] * NBX + bx] = (unsigned)min(rowcnt[reg], CAND_R);
    }
}

// K4: fused [exact | aggout], compaction-free phase E (R5-verified).
__global__ __launch_bounds__(256, 8) void k_post(
    const float* __restrict__ x, const float* __restrict__ sq,
    const unsigned* __restrict__ cntpart, const unsigned* __restrict__ cand,
    const float* __restrict__ U, const float* __restrict__ V,
    const float* __restrict__ W2, const float* __restrict__ b2,
    float* __restrict__ out)
{
    __shared__ union {
        struct { unsigned short vlist[4][VCAP];           // 1 KB
                 u64 ekeys[4][VCAP]; } e;                 // 4 KB
        struct { float ag[4][DOUT];                       // 2 KB
                 float w2t[32 * DOUT]; } a;               // 16 KB
    } sm;
    __shared__ int knn_s[4][KNN];                         // survives both phases
    int t = threadIdx.x;
    int w = t >> 6, l = t & 63;
    int row = blockIdx.x * 4 + w;
    // ---------------- phase E: exact top-16 ----------------
    {
        unsigned c[NBX];
        const unsigned* cp = cntpart + (size_t)row * NBX; // wave-uniform -> s_load
#pragma unroll
        for (int b = 0; b < NBX; ++b) c[b] = min(cp[b], (unsigned)CAND_R);
        const unsigned* crow = cand + (size_t)row * CAND_C;
        unsigned qq[NBX];
#pragma unroll
        for (int u = 0; u < NBX; ++u) {                   // all loads independent
            unsigned kv = crow[u * 64 + l];               // coalesced 256B/reg
            qq[u] = ((unsigned)l < c[u]) ? (kv >> 16) : 0xFFFFFFFFu;
        }
        unsigned p = 0;                                   // radix-select q16
#pragma unroll
        for (int b = 15; b >= 0; --b) {
            unsigned c16 = p | (1u << b);
            int cnt = 0;
#pragma unroll
            for (int u = 0; u < NBX; ++u)
                cnt += __popcll(__ballot(qq[u] < c16));
            if (cnt < 16) p = c16;
        }
        unsigned thr = p + DELTA_Q;                       // verify gate on q
        int nv = 0;
        u64 lm = (l == 63) ? 0xFFFFFFFFFFFFFFFFull >> 1 : (1ull << l) - 1ull;
#pragma unroll
        for (int u = 0; u < NBX; ++u) {
            bool pred = qq[u] <= thr;                     // invalid qq -> false
            u64 bal = __ballot(pred);
            int slot = nv + __popcll(bal & lm);
            if (pred && slot < VCAP) {
                unsigned kv = crow[u * 64 + l];           // reload j (L1/L2-hot)
                sm.e.vlist[w][slot] = (unsigned short)(kv & 0xFFFFu);
            }
            nv += __popcll(bal);
        }
        nv = min(nv, VCAP);
        __syncthreads();
        float sqi = sq[row];
        const float* xi = x + (size_t)row * DIN;          // wave-uniform
#pragma unroll
        for (int r = 0; r < VCAP / 64; ++r) {
            int v = l + 64 * r;
            if (v < nv) {
                int j = (int)sm.e.vlist[w][v];
                const float4* bj = (const float4*)(x + (size_t)j * DIN);
                float s0 = 0.f, s1 = 0.f, s2 = 0.f, s3 = 0.f;
                float4 rb[8];                             // 2x8 stages: same
#pragma unroll
                for (int q = 0; q < 8; ++q) rb[q] = bj[q];
#pragma unroll
                for (int q = 0; q < 8; ++q) {             // FMA order per acc
                    s0 = fmaf(xi[4 * q + 0], rb[q].x, s0);//  chain == r1-r11
                    s1 = fmaf(xi[4 * q + 1], rb[q].y, s1);
                    s2 = fmaf(xi[4 * q + 2], rb[q].z, s2);
                    s3 = fmaf(xi[4 * q + 3], rb[q].w, s3);
                }
#pragma unroll
                for (int q = 0; q < 8; ++q) rb[q] = bj[8 + q];
#pragma unroll
                for (int q = 0; q < 8; ++q) {
                    s0 = fmaf(xi[32 + 4 * q + 0], rb[q].x, s0);
                    s1 = fmaf(xi[32 + 4 * q + 1], rb[q].y, s1);
                    s2 = fmaf(xi[32 + 4 * q + 2], rb[q].z, s2);
                    s3 = fmaf(xi[32 + 4 * q + 3], rb[q].w, s3);
                }
                float d = (s0 + s1) + (s2 + s3);
                float dist = fmaf(-2.0f, d, sqi + sq[j]);
                sm.e.ekeys[w][v] = ((u64)mono(dist) << 32) | (unsigned)j;
            }
        }
#pragma unroll
        for (int r = 0; r < VCAP / 64; ++r) {             // all-pairs rank
            int v = l + 64 * r;
            if (v < nv) {
                u64 mykey = sm.e.ekeys[w][v];
                int rank = 0;
                for (int i = 0; i < nv; ++i)
                    rank += (sm.e.ekeys[w][i] < mykey) ? 1 : 0;
                if (rank < KNN)
                    knn_s[w][rank] = (int)(unsigned)(mykey & 0xFFFFFFFFull);
            }
        }
    }
    __syncthreads();                                      // e.* dead after this
    // ---------------- phase A: agg + W2 GEMM ----------------
    {
        int o = t & 127, g = t >> 7;                      // g in {0,1}: 2 rows
        int row0 = blockIdx.x * 4;
#pragma unroll
        for (int r = 0; r < 2; ++r) {
            int rr = g * 2 + r;
            int i = row0 + rr;
            float u = U[(size_t)i * DOUT + o];
            float acc = 0.f;
#pragma unroll
            for (int q = 0; q < KNN; ++q)                 // same q-order as ref
                acc += fmaxf(u + V[(size_t)knn_s[rr][q] * DOUT + o], 0.0f);
            sm.a.ag[rr][o] = acc * (1.0f / KNN);
        }
        float a2[2] = {0.f, 0.f};
#pragma unroll
        for (int tile = 0; tile < 4; ++tile) {
            __syncthreads();
#pragma unroll
            for (int u = 0; u < 4; ++u)                   // 16 KB coalesced stage
                ((float4*)sm.a.w2t)[t + u * 256] =
                    ((const float4*)(W2 + tile * 32 * DOUT))[t + u * 256];
            __syncthreads();
#pragma unroll 8
            for (int kk = 0; kk < 32; ++kk) {
                float wv = sm.a.w2t[kk * DOUT + o];
#pragma unroll
                for (int r = 0; r < 2; ++r)
                    a2[r] = fmaf(sm.a.ag[g * 2 + r][tile * 32 + kk], wv, a2[r]);
            }
        }
        float bb = b2[o];
#pragma unroll
        for (int r = 0; r < 2; ++r)
            out[(size_t)(row0 + g * 2 + r) * DOUT + o] = a2[r] + bb;
    }
}

extern "C" void kernel_launch(void* const* d_in, const int* in_sizes, int n_in,
                              void* d_out, int out_size, void* d_ws, size_t ws_size,
                              hipStream_t stream) {
    const float* x  = (const float*)d_in[0];
    const float* W1 = (const float*)d_in[1];
    const float* b1 = (const float*)d_in[2];
    const float* W2 = (const float*)d_in[3];
    const float* b2 = (const float*)d_in[4];
    float* out = (float*)d_out;

    char* ws = (char*)d_ws;
    float*          sq      = (float*)(ws);                      // 32 KB
    float*          sqs     = (float*)(ws + 32768);              // 8 KB
    float*          tauf    = (float*)(ws + 40960);              // 32 KB
    unsigned short* Xs      = (unsigned short*)(ws + 73728);     // 256 KB
    unsigned short* Xh      = (unsigned short*)(ws + 655360);    // 1 MB
    float*          U       = (float*)(ws + 2097152);            // 4 MB
    float*          V       = (float*)(ws + 6291456);            // 4 MB
    unsigned*       cntpart = (unsigned*)(ws + 10485760);        // 512 KB
    unsigned*       cand    = (unsigned*)(ws + 11534336);        // 32 MB
    // total ws use ~45 MB (<< 268 MB workspace)

    k_pre<<<N / 4, 256, 0, stream>>>(x, W1, b1, sq, sqs, Xh, Xs, U, V);
    k_pretau<<<N / 8, 512, 0, stream>>>(Xh, Xs, sq, sqs, tauf);
    k_main<<<dim3(NBX, 128), 256, 0, stream>>>(Xh, sq, tauf, cand, cntpart);
    k_post<<<N / 4, 256, 0, stream>>>(x, sq, cntpart, cand, U, V, W2, b2, out);
}

// Round 7
// 178.004 us; speedup vs baseline: 1.0789x; 1.0789x over previous
//
#include <hip/hip_runtime.h>

#define N 8192
#define DIN 64
#define DOUT 128
#define KNN 16
#define MSAMP 2048         /* presample columns, stride 4 */
#define NBX 16             /* j-split in main scan (512 j per region) */
#define NST 8              /* stages per block: NST*64 = 512 j */
#define CAND_R 64          /* slots per (row, bx) region == wave width */
#define CAND_C (NBX * CAND_R)   /* 1024 per row */
#define EPS 1.0f           /* candidate-gate margin (passed r8-r11) */
#define DELTA_Q 64         /* verify-gate margin: 0.5 in dist units */
#define VCAP 128           /* verify-list capacity (expect ~45, >10 sigma) */

typedef unsigned long long u64;
typedef __attribute__((ext_vector_type(8))) short bf16x8;
typedef __attribute__((ext_vector_type(4))) float floatx4;

__device__ __forceinline__ unsigned mono(float f) {
    unsigned u = __float_as_uint(f);
    return (u & 0x80000000u) ? ~u : (u | 0x80000000u);
}
__device__ __forceinline__ unsigned short f2bf(float f) {   // RNE float->bf16
    unsigned u = __float_as_uint(f);
    return (unsigned short)((u + 0x7FFFu + ((u >> 16) & 1u)) >> 16);
}
__device__ __forceinline__ unsigned qdist(float dist) {     // round-up quant
    int q = (int)(dist * 128.0f) + 2;
    q = max(q, 0); return (unsigned)min(q, 65535);
}

// K1: fused pre (R6-verified).  4 rows/block -> 8 blocks/CU.  Emits Xs:
// dense copy of sampled rows for k_pretau's A-gathers.
__global__ __launch_bounds__(256, 8) void k_pre(const float* __restrict__ x,
                                                const float* __restrict__ W1,
                                                const float* __restrict__ b1,
                                                float* __restrict__ sq,
                                                float* __restrict__ sqs,
                                                unsigned short* __restrict__ Xh,
                                                unsigned short* __restrict__ Xs,
                                                float* __restrict__ U,
                                                float* __restrict__ V) {
    __shared__ float xs[4][DIN];
    int t = threadIdx.x;
    int r0 = blockIdx.x * 4;
    if (t < 64) {
        float4 xv = ((const float4*)x)[(size_t)r0 * (DIN / 4) + t];
        ((float4*)xs)[t] = xv;
        ushort4 h4;
        h4.x = f2bf(xv.x); h4.y = f2bf(xv.y);
        h4.z = f2bf(xv.z); h4.w = f2bf(xv.w);
        *(ushort4*)&Xh[r0 * DIN + t * 4] = h4;
        if (t < 16)                                  // row r0 is the sampled one
            *(ushort4*)&Xs[(r0 >> 2) * DIN + t * 4] = h4;
    }
    __syncthreads();
    if (t < 4) {
        const float4* xr = (const float4*)xs[t];
        float s0 = 0.f, s1 = 0.f, s2 = 0.f, s3 = 0.f;
#pragma unroll
        for (int q = 0; q < DIN / 4; ++q) {
            float4 a = xr[q];
            s0 = fmaf(a.x, a.x, s0); s1 = fmaf(a.y, a.y, s1);
            s2 = fmaf(a.z, a.z, s2); s3 = fmaf(a.w, a.w, s3);
        }
        float sv = (s0 + s1) + (s2 + s3);
        sq[r0 + t] = sv;
        if (t == 0) sqs[r0 >> 2] = sv;               // sampled rows j = 4*scol
    }
    int o = t & 127, g = t >> 7;                     // g in {0,1}: rows g*2+u
    float aU[2], aV[2];
#pragma unroll
    for (int u = 0; u < 2; ++u) { aU[u] = 0.f; aV[u] = 0.f; }
    for (int kk = 0; kk < DIN; ++kk) {
        float whi = W1[kk * DOUT + o];
        float wlo = W1[(DIN + kk) * DOUT + o];
        float wd = whi - wlo;
#pragma unroll
        for (int u = 0; u < 2; ++u) {
            float xvv = xs[g * 2 + u][kk];
            aU[u] = fmaf(xvv, wd, aU[u]);
            aV[u] = fmaf(xvv, wlo, aV[u]);
        }
    }
    float bb = b1[o];
#pragma unroll
    for (int u = 0; u < 2; ++u) {
        int r = r0 + g * 2 + u;
        U[(size_t)r * DOUT + o] = aU[u] + bb;
        V[(size_t)r * DOUT + o] = aV[u];
    }
}

// K2: fused presample + tau.  BACK to 16 i-rows/block (512 blocks: the
// A-sweep over all 2048 sampled rows is per-block fixed cost -> more rows
// amortize it; R6's 8-row split doubled it and regressed).  A-frags from
// dense Xs.  RADIX FIX (R6 post-mortem: VGPR=20 proved the compiler demoted
// v[32] and re-read LDS 512x per row): load each row's 2048 q as 4x
// ds_read_b128/lane (contiguous 16B -> conflict-free), unpack ONCE to 32
// u32 regs, pin with asm(""):"+v" (opaque asm forbids LDS remat).  Both
// rows' 16-round chains interleaved for ILP.  Same multiset per row ->
// tau bit-identical.
__global__ __launch_bounds__(512, 4) void k_pretau(const unsigned short* __restrict__ Xh,
                                                   const unsigned short* __restrict__ Xs,
                                                   const float* __restrict__ sq,
                                                   const float* __restrict__ sqs,
                                                   float* __restrict__ tauf) {
    __shared__ __align__(16) unsigned short qls[16 * MSAMP];   // 64 KB exactly
    int tid = threadIdx.x, w = tid >> 6, l = tid & 63;
    int m = l & 15, quad = l >> 4, ko = quad * 8;
    int rt = blockIdx.x;
    int irow = rt * 16 + m;
    size_t arow = (size_t)irow * DIN;
    bf16x8 iH0 = *(const bf16x8*)(Xh + arow + ko);   // i-row frag (B)
    bf16x8 iH1 = *(const bf16x8*)(Xh + arow + 32 + ko);
    float si = sq[irow];
    int swz = (m & 7) << 4;
    for (int it = 0; it < 16; ++it) {
        int s16 = w * 256 + it * 16;                 // scol tile base
        const unsigned short* sp = Xs + (size_t)(s16 + m) * DIN;  // dense rows
        bf16x8 sH0 = *(const bf16x8*)(sp + ko);      // sampled (A)
        bf16x8 sH1 = *(const bf16x8*)(sp + 32 + ko);
        floatx4 acc = {0.f, 0.f, 0.f, 0.f};
        acc = __builtin_amdgcn_mfma_f32_16x16x32_bf16(sH0, iH0, acc, 0, 0, 0);
        acc = __builtin_amdgcn_mfma_f32_16x16x32_bf16(sH1, iH1, acc, 0, 0, 0);
        int sc0 = s16 + quad * 4;                    // 4 consecutive scols
        float4 sj = *(const float4*)(sqs + sc0);
        unsigned q0 = qdist(fmaf(-2.0f, acc[0], si + sj.x));
        unsigned q1 = qdist(fmaf(-2.0f, acc[1], si + sj.y));
        unsigned q2 = qdist(fmaf(-2.0f, acc[2], si + sj.z));
        unsigned q3 = qdist(fmaf(-2.0f, acc[3], si + sj.w));
        u64 pk = (u64)q0 | ((u64)q1 << 16) | ((u64)q2 << 32) | ((u64)q3 << 48);
        *(u64*)&qls[m * MSAMP + (sc0 ^ swz)] = pk;   // multiset-preserving
    }
    __syncthreads();
    // wave w radix-selects rows {2w, 2w+1}; values register-resident.
    int rA = 2 * w, rB = 2 * w + 1;
    const uint4* qv = (const uint4*)qls;             // 16B units
    unsigned vA[32], vB[32];
#pragma unroll
    for (int k = 0; k < 4; ++k) {
        uint4 ta = qv[rA * 256 + k * 64 + l];        // lane-contiguous 16B
        uint4 tb = qv[rB * 256 + k * 64 + l];
        vA[k*8+0] = ta.x & 0xFFFFu; vA[k*8+1] = ta.x >> 16;
        vA[k*8+2] = ta.y & 0xFFFFu; vA[k*8+3] = ta.y >> 16;
        vA[k*8+4] = ta.z & 0xFFFFu; vA[k*8+5] = ta.z >> 16;
        vA[k*8+6] = ta.w & 0xFFFFu; vA[k*8+7] = ta.w >> 16;
        vB[k*8+0] = tb.x & 0xFFFFu; vB[k*8+1] = tb.x >> 16;
        vB[k*8+2] = tb.y & 0xFFFFu; vB[k*8+3] = tb.y >> 16;
        vB[k*8+4] = tb.z & 0xFFFFu; vB[k*8+5] = tb.z >> 16;
        vB[k*8+6] = tb.w & 0xFFFFu; vB[k*8+7] = tb.w >> 16;
    }
#pragma unroll
    for (int i = 0; i < 32; ++i) {                   // pin in VGPRs: opaque asm
        asm volatile("" : "+v"(vA[i]));              // makes LDS-remat illegal
        asm volatile("" : "+v"(vB[i]));
    }
    unsigned pA = 0, pB = 0;                         // invariant: #{q < p} < 16
#pragma unroll
    for (int b = 15; b >= 0; --b) {
        unsigned cA = pA | (1u << b), cB = pB | (1u << b);
        int na = 0, nb = 0;
#pragma unroll
        for (int i = 0; i < 32; ++i) {               // two independent chains
            na += __popcll(__ballot(vA[i] < cA));
            nb += __popcll(__ballot(vB[i] < cB));
        }
        if (na < 16) pA = cA;                        // wave-uniform
        if (nb < 16) pB = cB;
    }
    if (l == 0) {
        tauf[rt * 16 + rA] = (float)pA * (1.0f / 128.0f);
        tauf[rt * 16 + rB] = (float)pB * (1.0f / 128.0f);
    }
}

// K3: MFMA main scan (R4 geometry: NBX=16, 8 blocks/CU).
__global__ __launch_bounds__(256, 8) void k_main(const unsigned short* __restrict__ Xh,
                                                 const float* __restrict__ sq,
                                                 const float* __restrict__ tauf,
                                                 unsigned* __restrict__ cand,
                                                 unsigned* __restrict__ cntpart) {
    __shared__ __align__(16) short ldsH[64 * 72];
    int tid = threadIdx.x, w = tid >> 6, l = tid & 63;
    int m = l & 15, ko = (l >> 4) * 8;
    int bx = blockIdx.x;
    int rt = blockIdx.y * 4 + w;
    size_t arow = (size_t)(rt * 16 + m) * DIN;
    bf16x8 aH0 = *(const bf16x8*)(Xh + arow + ko);
    bf16x8 aH1 = *(const bf16x8*)(Xh + arow + 32 + ko);
    int rg[4]; float T[4]; float si[4]; int rowcnt[4];
#pragma unroll
    for (int reg = 0; reg < 4; ++reg) {
        rg[reg] = rt * 16 + (l >> 4) * 4 + reg;
        si[reg] = sq[rg[reg]];
        T[reg] = tauf[rg[reg]] + EPS - si[reg];
        rowcnt[reg] = 0;
    }
    int qs = l & 48;
    unsigned lmask = (1u << (l & 15)) - 1u;
    int srw = tid >> 3, scol8 = (tid & 7) * 8;

    for (int st = 0; st < NST; ++st) {
        int jbase = bx * (NST * 64) + st * 64;
        __syncthreads();
        *(bf16x8*)&ldsH[srw * 72 + scol8] =
            *(const bf16x8*)(Xh + (size_t)(jbase + srw) * DIN + scol8);
        *(bf16x8*)&ldsH[(srw + 32) * 72 + scol8] =
            *(const bf16x8*)(Xh + (size_t)(jbase + srw + 32) * DIN + scol8);
        __syncthreads();
#pragma unroll
        for (int it = 0; it < 4; ++it) {
            int br = it * 16 + m;
            bf16x8 bH0 = *(const bf16x8*)&ldsH[br * 72 + ko];
            bf16x8 bH1 = *(const bf16x8*)&ldsH[br * 72 + 32 + ko];
            floatx4 acc = {0.f, 0.f, 0.f, 0.f};
            acc = __builtin_amdgcn_mfma_f32_16x16x32_bf16(aH0, bH0, acc, 0, 0, 0);
            acc = __builtin_amdgcn_mfma_f32_16x16x32_bf16(aH1, bH1, acc, 0, 0, 0);
            int jcol = jbase + it * 16 + m;
            float sqj = sq[jcol];
#pragma unroll
            for (int reg = 0; reg < 4; ++reg) {
                float tv = fmaf(-2.0f, acc[reg], sqj);   // dist - si
                bool pass = tv <= T[reg];
                u64 bal = __ballot(pass);
                if (bal) {                               // skip empty
                    unsigned m16 = (unsigned)((bal >> qs) & 0xFFFFull);
                    if (pass) {
                        int slot = rowcnt[reg] + __popc(m16 & lmask);
                        if (slot < CAND_R)
                            cand[(size_t)rg[reg] * CAND_C + bx * CAND_R + slot] =
                                (qdist(tv + si[reg]) << 16) | (unsigned)jcol;
                    }
                    rowcnt[reg] += __popc(m16);
                }
            }
        }
    }
    if ((l & 15) == 0) {
#pragma unroll
        for (int reg = 0; reg < 4; ++reg)
            cntpart[rg[reg] * NBX + bx] = (unsigned)min(rowcnt[reg], CAND_R);
    }
}

// K4: fused [exact | aggout], compaction-free phase E (R5-verified).
__global__ __launch_bounds__(256, 8) void k_post(
    const float* __restrict__ x, const float* __restrict__ sq,
    const unsigned* __restrict__ cntpart, const unsigned* __restrict__ cand,
    const float* __restrict__ U, const float* __restrict__ V,
    const float* __restrict__ W2, const float* __restrict__ b2,
    float* __restrict__ out)
{
    __shared__ union {
        struct { unsigned short vlist[4][VCAP];           // 1 KB
                 u64 ekeys[4][VCAP]; } e;                 // 4 KB
        struct { float ag[4][DOUT];                       // 2 KB
                 float w2t[32 * DOUT]; } a;               // 16 KB
    } sm;
    __shared__ int knn_s[4][KNN];                         // survives both phases
    int t = threadIdx.x;
    int w = t >> 6, l = t & 63;
    int row = blockIdx.x * 4 + w;
    // ---------------- phase E: exact top-16 ----------------
    {
        unsigned c[NBX];
        const unsigned* cp = cntpart + (size_t)row * NBX; // wave-uniform -> s_load
#pragma unroll
        for (int b = 0; b < NBX; ++b) c[b] = min(cp[b], (unsigned)CAND_R);
        const unsigned* crow = cand + (size_t)row * CAND_C;
        unsigned qq[NBX];
#pragma unroll
        for (int u = 0; u < NBX; ++u) {                   // all loads independent
            unsigned kv = crow[u * 64 + l];               // coalesced 256B/reg
            qq[u] = ((unsigned)l < c[u]) ? (kv >> 16) : 0xFFFFFFFFu;
        }
        unsigned p = 0;                                   // radix-select q16
#pragma unroll
        for (int b = 15; b >= 0; --b) {
            unsigned c16 = p | (1u << b);
            int cnt = 0;
#pragma unroll
            for (int u = 0; u < NBX; ++u)
                cnt += __popcll(__ballot(qq[u] < c16));
            if (cnt < 16) p = c16;
        }
        unsigned thr = p + DELTA_Q;                       // verify gate on q
        int nv = 0;
        u64 lm = (l == 63) ? 0xFFFFFFFFFFFFFFFFull >> 1 : (1ull << l) - 1ull;
#pragma unroll
        for (int u = 0; u < NBX; ++u) {
            bool pred = qq[u] <= thr;                     // invalid qq -> false
            u64 bal = __ballot(pred);
            int slot = nv + __popcll(bal & lm);
            if (pred && slot < VCAP) {
                unsigned kv = crow[u * 64 + l];           // reload j (L1/L2-hot)
                sm.e.vlist[w][slot] = (unsigned short)(kv & 0xFFFFu);
            }
            nv += __popcll(bal);
        }
        nv = min(nv, VCAP);
        __syncthreads();
        float sqi = sq[row];
        const float* xi = x + (size_t)row * DIN;          // wave-uniform
#pragma unroll
        for (int r = 0; r < VCAP / 64; ++r) {
            int v = l + 64 * r;
            if (v < nv) {
                int j = (int)sm.e.vlist[w][v];
                const float4* bj = (const float4*)(x + (size_t)j * DIN);
                float s0 = 0.f, s1 = 0.f, s2 = 0.f, s3 = 0.f;
                float4 rb[8];                             // 2x8 stages: same
#pragma unroll
                for (int q = 0; q < 8; ++q) rb[q] = bj[q];
#pragma unroll
                for (int q = 0; q < 8; ++q) {             // FMA order per acc
                    s0 = fmaf(xi[4 * q + 0], rb[q].x, s0);//  chain == r1-r11
                    s1 = fmaf(xi[4 * q + 1], rb[q].y, s1);
                    s2 = fmaf(xi[4 * q + 2], rb[q].z, s2);
                    s3 = fmaf(xi[4 * q + 3], rb[q].w, s3);
                }
#pragma unroll
                for (int q = 0; q < 8; ++q) rb[q] = bj[8 + q];
#pragma unroll
                for (int q = 0; q < 8; ++q) {
                    s0 = fmaf(xi[32 + 4 * q + 0], rb[q].x, s0);
                    s1 = fmaf(xi[32 + 4 * q + 1], rb[q].y, s1);
                    s2 = fmaf(xi[32 + 4 * q + 2], rb[q].z, s2);
                    s3 = fmaf(xi[32 + 4 * q + 3], rb[q].w, s3);
                }
                float d = (s0 + s1) + (s2 + s3);
                float dist = fmaf(-2.0f, d, sqi + sq[j]);
                sm.e.ekeys[w][v] = ((u64)mono(dist) << 32) | (unsigned)j;
            }
        }
#pragma unroll
        for (int r = 0; r < VCAP / 64; ++r) {             // all-pairs rank
            int v = l + 64 * r;
            if (v < nv) {
                u64 mykey = sm.e.ekeys[w][v];
                int rank = 0;
                for (int i = 0; i < nv; ++i)
                    rank += (sm.e.ekeys[w][i] < mykey) ? 1 : 0;
                if (rank < KNN)
                    knn_s[w][rank] = (int)(unsigned)(mykey & 0xFFFFFFFFull);
            }
        }
    }
    __syncthreads();                                      // e.* dead after this
    // ---------------- phase A: agg + W2 GEMM ----------------
    {
        int o = t & 127, g = t >> 7;                      // g in {0,1}: 2 rows
        int row0 = blockIdx.x * 4;
#pragma unroll
        for (int r = 0; r < 2; ++r) {
            int rr = g * 2 + r;
            int i = row0 + rr;
            float u = U[(size_t)i * DOUT + o];
            float acc = 0.f;
#pragma unroll
            for (int q = 0; q < KNN; ++q)                 // same q-order as ref
                acc += fmaxf(u + V[(size_t)knn_s[rr][q] * DOUT + o], 0.0f);
            sm.a.ag[rr][o] = acc * (1.0f / KNN);
        }
        float a2[2] = {0.f, 0.f};
#pragma unroll
        for (int tile = 0; tile < 4; ++tile) {
            __syncthreads();
#pragma unroll
            for (int u = 0; u < 4; ++u)                   // 16 KB coalesced stage
                ((float4*)sm.a.w2t)[t + u * 256] =
                    ((const float4*)(W2 + tile * 32 * DOUT))[t + u * 256];
            __syncthreads();
#pragma unroll 8
            for (int kk = 0; kk < 32; ++kk) {
                float wv = sm.a.w2t[kk * DOUT + o];
#pragma unroll
                for (int r = 0; r < 2; ++r)
                    a2[r] = fmaf(sm.a.ag[g * 2 + r][tile * 32 + kk], wv, a2[r]);
            }
        }
        float bb = b2[o];
#pragma unroll
        for (int r = 0; r < 2; ++r)
            out[(size_t)(row0 + g * 2 + r) * DOUT + o] = a2[r] + bb;
    }
}

extern "C" void kernel_launch(void* const* d_in, const int* in_sizes, int n_in,
                              void* d_out, int out_size, void* d_ws, size_t ws_size,
                              hipStream_t stream) {
    const float* x  = (const float*)d_in[0];
    const float* W1 = (const float*)d_in[1];
    const float* b1 = (const float*)d_in[2];
    const float* W2 = (const float*)d_in[3];
    const float* b2 = (const float*)d_in[4];
    float* out = (float*)d_out;

    char* ws = (char*)d_ws;
    float*          sq      = (float*)(ws);                      // 32 KB
    float*          sqs     = (float*)(ws + 32768);              // 8 KB
    float*          tauf    = (float*)(ws + 40960);              // 32 KB
    unsigned short* Xs      = (unsigned short*)(ws + 73728);     // 256 KB
    unsigned short* Xh      = (unsigned short*)(ws + 655360);    // 1 MB
    float*          U       = (float*)(ws + 2097152);            // 4 MB
    float*          V       = (float*)(ws + 6291456);            // 4 MB
    unsigned*       cntpart = (unsigned*)(ws + 10485760);        // 512 KB
    unsigned*       cand    = (unsigned*)(ws + 11534336);        // 32 MB
    // total ws use ~45 MB (<< 268 MB workspace)

    k_pre<<<N / 4, 256, 0, stream>>>(x, W1, b1, sq, sqs, Xh, Xs, U, V);
    k_pretau<<<N / 16, 512, 0, stream>>>(Xh, Xs, sq, sqs, tauf);
    k_main<<<dim3(NBX, 128), 256, 0, stream>>>(Xh, sq, tauf, cand, cntpart);
    k_post<<<N / 4, 256, 0, stream>>>(x, sq, cntpart, cand, U, V, W2, b2, out);
}

// Round 8
// 176.353 us; speedup vs baseline: 1.0890x; 1.0094x over previous
//
#include <hip/hip_runtime.h>

#define N 8192
#define DIN 64
#define DOUT 128
#define KNN 16
#define MSAMP 2048         /* presample columns, stride 4 */
#define NBX 16             /* j-split in main scan (512 j per region) */
#define NST 8              /* stages per block: NST*64 = 512 j */
#define CAND_R 64          /* slots per (row, bx) region == wave width */
#define CAND_C (NBX * CAND_R)   /* 1024 per row */
#define EPS 1.0f           /* candidate-gate margin (passed r8-r11) */
#define DELTA_Q 64         /* verify-gate margin: 0.5 in dist units */
#define VCAP 128           /* verify-list capacity (expect ~45, >10 sigma) */

typedef unsigned long long u64;
typedef __attribute__((ext_vector_type(8))) short bf16x8;
typedef __attribute__((ext_vector_type(4))) float floatx4;

__device__ __forceinline__ unsigned mono(float f) {
    unsigned u = __float_as_uint(f);
    return (u & 0x80000000u) ? ~u : (u | 0x80000000u);
}
__device__ __forceinline__ unsigned short f2bf(float f) {   // RNE float->bf16
    unsigned u = __float_as_uint(f);
    return (unsigned short)((u + 0x7FFFu + ((u >> 16) & 1u)) >> 16);
}
__device__ __forceinline__ unsigned qdist(float dist) {     // round-up quant
    int q = (int)(dist * 128.0f) + 2;
    q = max(q, 0); return (unsigned)min(q, 65535);
}

// K1: fused pre.  8 rows/block (R7 post-mortem: 4-row = 268 MB of W1 L2
// replication at 2:4 load:FMA -> W1-bound; 16-row = 25% occupancy.  8-row
// = 134 MB at 2:8 with 50% occupancy: the middle of the tradeoff curve).
// Emits Xs (dense sampled rows, 2 per block) for k_pretau.  Per-output FMA
// chains identical -> U,V,sq,Xh,Xs bit-identical.
__global__ __launch_bounds__(256, 4) void k_pre(const float* __restrict__ x,
                                                const float* __restrict__ W1,
                                                const float* __restrict__ b1,
                                                float* __restrict__ sq,
                                                float* __restrict__ sqs,
                                                unsigned short* __restrict__ Xh,
                                                unsigned short* __restrict__ Xs,
                                                float* __restrict__ U,
                                                float* __restrict__ V) {
    __shared__ float xs[8][DIN];
    int t = threadIdx.x;
    int r0 = blockIdx.x * 8;
    if (t < 128) {
        float4 xv = ((const float4*)x)[(size_t)r0 * (DIN / 4) + t];
        ((float4*)xs)[t] = xv;
        ushort4 h4;
        h4.x = f2bf(xv.x); h4.y = f2bf(xv.y);
        h4.z = f2bf(xv.z); h4.w = f2bf(xv.w);
        *(ushort4*)&Xh[r0 * DIN + t * 4] = h4;
    }
    __syncthreads();
    if (t < 32) {                                    // sampled rows r0, r0+4
        int s = t >> 4, c = t & 15;
        const float* xr = xs[s * 4];
        ushort4 h4;
        h4.x = f2bf(xr[c * 4 + 0]); h4.y = f2bf(xr[c * 4 + 1]);
        h4.z = f2bf(xr[c * 4 + 2]); h4.w = f2bf(xr[c * 4 + 3]);
        *(ushort4*)&Xs[(size_t)(2 * blockIdx.x + s) * DIN + c * 4] = h4;
    }
    if (t < 8) {
        const float4* xr = (const float4*)xs[t];
        float s0 = 0.f, s1 = 0.f, s2 = 0.f, s3 = 0.f;
#pragma unroll
        for (int q = 0; q < DIN / 4; ++q) {
            float4 a = xr[q];
            s0 = fmaf(a.x, a.x, s0); s1 = fmaf(a.y, a.y, s1);
            s2 = fmaf(a.z, a.z, s2); s3 = fmaf(a.w, a.w, s3);
        }
        float sv = (s0 + s1) + (s2 + s3);
        sq[r0 + t] = sv;
        if ((t & 3) == 0) sqs[(r0 + t) >> 2] = sv;   // sampled rows j = 4*scol
    }
    int o = t & 127, g = t >> 7;                     // g in {0,1}: rows g*4+u
    float aU[4], aV[4];
#pragma unroll
    for (int u = 0; u < 4; ++u) { aU[u] = 0.f; aV[u] = 0.f; }
    for (int kk = 0; kk < DIN; ++kk) {
        float whi = W1[kk * DOUT + o];
        float wlo = W1[(DIN + kk) * DOUT + o];
        float wd = whi - wlo;
#pragma unroll
        for (int u = 0; u < 4; ++u) {
            float xvv = xs[g * 4 + u][kk];
            aU[u] = fmaf(xvv, wd, aU[u]);
            aV[u] = fmaf(xvv, wlo, aV[u]);
        }
    }
    float bb = b1[o];
#pragma unroll
    for (int u = 0; u < 4; ++u) {
        int r = r0 + g * 4 + u;
        U[(size_t)r * DOUT + o] = aU[u] + bb;
        V[(size_t)r * DOUT + o] = aV[u];
    }
}

// K2: fused presample + tau (R7-verified).  16 i-rows/block, dense Xs
// A-gathers, register-resident radix (asm-pinned; R6's VGPR=20 proved the
// LDS-demotion failure mode).  Same multiset per row -> tau bit-identical.
__global__ __launch_bounds__(512, 4) void k_pretau(const unsigned short* __restrict__ Xh,
                                                   const unsigned short* __restrict__ Xs,
                                                   const float* __restrict__ sq,
                                                   const float* __restrict__ sqs,
                                                   float* __restrict__ tauf) {
    __shared__ __align__(16) unsigned short qls[16 * MSAMP];   // 64 KB exactly
    int tid = threadIdx.x, w = tid >> 6, l = tid & 63;
    int m = l & 15, quad = l >> 4, ko = quad * 8;
    int rt = blockIdx.x;
    int irow = rt * 16 + m;
    size_t arow = (size_t)irow * DIN;
    bf16x8 iH0 = *(const bf16x8*)(Xh + arow + ko);   // i-row frag (B)
    bf16x8 iH1 = *(const bf16x8*)(Xh + arow + 32 + ko);
    float si = sq[irow];
    int swz = (m & 7) << 4;
    for (int it = 0; it < 16; ++it) {
        int s16 = w * 256 + it * 16;                 // scol tile base
        const unsigned short* sp = Xs + (size_t)(s16 + m) * DIN;  // dense rows
        bf16x8 sH0 = *(const bf16x8*)(sp + ko);      // sampled (A)
        bf16x8 sH1 = *(const bf16x8*)(sp + 32 + ko);
        floatx4 acc = {0.f, 0.f, 0.f, 0.f};
        acc = __builtin_amdgcn_mfma_f32_16x16x32_bf16(sH0, iH0, acc, 0, 0, 0);
        acc = __builtin_amdgcn_mfma_f32_16x16x32_bf16(sH1, iH1, acc, 0, 0, 0);
        int sc0 = s16 + quad * 4;                    // 4 consecutive scols
        float4 sj = *(const float4*)(sqs + sc0);
        unsigned q0 = qdist(fmaf(-2.0f, acc[0], si + sj.x));
        unsigned q1 = qdist(fmaf(-2.0f, acc[1], si + sj.y));
        unsigned q2 = qdist(fmaf(-2.0f, acc[2], si + sj.z));
        unsigned q3 = qdist(fmaf(-2.0f, acc[3], si + sj.w));
        u64 pk = (u64)q0 | ((u64)q1 << 16) | ((u64)q2 << 32) | ((u64)q3 << 48);
        *(u64*)&qls[m * MSAMP + (sc0 ^ swz)] = pk;   // multiset-preserving
    }
    __syncthreads();
    // wave w radix-selects rows {2w, 2w+1}; values register-resident.
    int rA = 2 * w, rB = 2 * w + 1;
    const uint4* qv = (const uint4*)qls;             // 16B units
    unsigned vA[32], vB[32];
#pragma unroll
    for (int k = 0; k < 4; ++k) {
        uint4 ta = qv[rA * 256 + k * 64 + l];        // lane-contiguous 16B
        uint4 tb = qv[rB * 256 + k * 64 + l];
        vA[k*8+0] = ta.x & 0xFFFFu; vA[k*8+1] = ta.x >> 16;
        vA[k*8+2] = ta.y & 0xFFFFu; vA[k*8+3] = ta.y >> 16;
        vA[k*8+4] = ta.z & 0xFFFFu; vA[k*8+5] = ta.z >> 16;
        vA[k*8+6] = ta.w & 0xFFFFu; vA[k*8+7] = ta.w >> 16;
        vB[k*8+0] = tb.x & 0xFFFFu; vB[k*8+1] = tb.x >> 16;
        vB[k*8+2] = tb.y & 0xFFFFu; vB[k*8+3] = tb.y >> 16;
        vB[k*8+4] = tb.z & 0xFFFFu; vB[k*8+5] = tb.z >> 16;
        vB[k*8+6] = tb.w & 0xFFFFu; vB[k*8+7] = tb.w >> 16;
    }
#pragma unroll
    for (int i = 0; i < 32; ++i) {                   // pin in VGPRs: opaque asm
        asm volatile("" : "+v"(vA[i]));              // makes LDS-remat illegal
        asm volatile("" : "+v"(vB[i]));
    }
    unsigned pA = 0, pB = 0;                         // invariant: #{q < p} < 16
#pragma unroll
    for (int b = 15; b >= 0; --b) {
        unsigned cA = pA | (1u << b), cB = pB | (1u << b);
        int na = 0, nb = 0;
#pragma unroll
        for (int i = 0; i < 32; ++i) {               // two independent chains
            na += __popcll(__ballot(vA[i] < cA));
            nb += __popcll(__ballot(vB[i] < cB));
        }
        if (na < 16) pA = cA;                        // wave-uniform
        if (nb < 16) pB = cB;
    }
    if (l == 0) {
        tauf[rt * 16 + rA] = (float)pA * (1.0f / 128.0f);
        tauf[rt * 16 + rB] = (float)pB * (1.0f / 128.0f);
    }
}

// K3: MFMA main scan (R4 geometry: NBX=16, 8 blocks/CU).
__global__ __launch_bounds__(256, 8) void k_main(const unsigned short* __restrict__ Xh,
                                                 const float* __restrict__ sq,
                                                 const float* __restrict__ tauf,
                                                 unsigned* __restrict__ cand,
                                                 unsigned* __restrict__ cntpart) {
    __shared__ __align__(16) short ldsH[64 * 72];
    int tid = threadIdx.x, w = tid >> 6, l = tid & 63;
    int m = l & 15, ko = (l >> 4) * 8;
    int bx = blockIdx.x;
    int rt = blockIdx.y * 4 + w;
    size_t arow = (size_t)(rt * 16 + m) * DIN;
    bf16x8 aH0 = *(const bf16x8*)(Xh + arow + ko);
    bf16x8 aH1 = *(const bf16x8*)(Xh + arow + 32 + ko);
    int rg[4]; float T[4]; float si[4]; int rowcnt[4];
#pragma unroll
    for (int reg = 0; reg < 4; ++reg) {
        rg[reg] = rt * 16 + (l >> 4) * 4 + reg;
        si[reg] = sq[rg[reg]];
        T[reg] = tauf[rg[reg]] + EPS - si[reg];
        rowcnt[reg] = 0;
    }
    int qs = l & 48;
    unsigned lmask = (1u << (l & 15)) - 1u;
    int srw = tid >> 3, scol8 = (tid & 7) * 8;

    for (int st = 0; st < NST; ++st) {
        int jbase = bx * (NST * 64) + st * 64;
        __syncthreads();
        *(bf16x8*)&ldsH[srw * 72 + scol8] =
            *(const bf16x8*)(Xh + (size_t)(jbase + srw) * DIN + scol8);
        *(bf16x8*)&ldsH[(srw + 32) * 72 + scol8] =
            *(const bf16x8*)(Xh + (size_t)(jbase + srw + 32) * DIN + scol8);
        __syncthreads();
#pragma unroll
        for (int it = 0; it < 4; ++it) {
            int br = it * 16 + m;
            bf16x8 bH0 = *(const bf16x8*)&ldsH[br * 72 + ko];
            bf16x8 bH1 = *(const bf16x8*)&ldsH[br * 72 + 32 + ko];
            floatx4 acc = {0.f, 0.f, 0.f, 0.f};
            acc = __builtin_amdgcn_mfma_f32_16x16x32_bf16(aH0, bH0, acc, 0, 0, 0);
            acc = __builtin_amdgcn_mfma_f32_16x16x32_bf16(aH1, bH1, acc, 0, 0, 0);
            int jcol = jbase + it * 16 + m;
            float sqj = sq[jcol];
#pragma unroll
            for (int reg = 0; reg < 4; ++reg) {
                float tv = fmaf(-2.0f, acc[reg], sqj);   // dist - si
                bool pass = tv <= T[reg];
                u64 bal = __ballot(pass);
                if (bal) {                               // skip empty
                    unsigned m16 = (unsigned)((bal >> qs) & 0xFFFFull);
                    if (pass) {
                        int slot = rowcnt[reg] + __popc(m16 & lmask);
                        if (slot < CAND_R)
                            cand[(size_t)rg[reg] * CAND_C + bx * CAND_R + slot] =
                                (qdist(tv + si[reg]) << 16) | (unsigned)jcol;
                    }
                    rowcnt[reg] += __popc(m16);
                }
            }
        }
    }
    if ((l & 15) == 0) {
#pragma unroll
        for (int reg = 0; reg < 4; ++reg)
            cntpart[rg[reg] * NBX + bx] = (unsigned)min(rowcnt[reg], CAND_R);
    }
}

// K4: fused [exact | aggout], compaction-free phase E (R5-verified).
__global__ __launch_bounds__(256, 8) void k_post(
    const float* __restrict__ x, const float* __restrict__ sq,
    const unsigned* __restrict__ cntpart, const unsigned* __restrict__ cand,
    const float* __restrict__ U, const float* __restrict__ V,
    const float* __restrict__ W2, const float* __restrict__ b2,
    float* __restrict__ out)
{
    __shared__ union {
        struct { unsigned short vlist[4][VCAP];           // 1 KB
                 u64 ekeys[4][VCAP]; } e;                 // 4 KB
        struct { float ag[4][DOUT];                       // 2 KB
                 float w2t[32 * DOUT]; } a;               // 16 KB
    } sm;
    __shared__ int knn_s[4][KNN];                         // survives both phases
    int t = threadIdx.x;
    int w = t >> 6, l = t & 63;
    int row = blockIdx.x * 4 + w;
    // ---------------- phase E: exact top-16 ----------------
    {
        unsigned c[NBX];
        const unsigned* cp = cntpart + (size_t)row * NBX; // wave-uniform -> s_load
#pragma unroll
        for (int b = 0; b < NBX; ++b) c[b] = min(cp[b], (unsigned)CAND_R);
        const unsigned* crow = cand + (size_t)row * CAND_C;
        unsigned qq[NBX];
#pragma unroll
        for (int u = 0; u < NBX; ++u) {                   // all loads independent
            unsigned kv = crow[u * 64 + l];               // coalesced 256B/reg
            qq[u] = ((unsigned)l < c[u]) ? (kv >> 16) : 0xFFFFFFFFu;
        }
        unsigned p = 0;                                   // radix-select q16
#pragma unroll
        for (int b = 15; b >= 0; --b) {
            unsigned c16 = p | (1u << b);
            int cnt = 0;
#pragma unroll
            for (int u = 0; u < NBX; ++u)
                cnt += __popcll(__ballot(qq[u] < c16));
            if (cnt < 16) p = c16;
        }
        unsigned thr = p + DELTA_Q;                       // verify gate on q
        int nv = 0;
        u64 lm = (l == 63) ? 0xFFFFFFFFFFFFFFFFull >> 1 : (1ull << l) - 1ull;
#pragma unroll
        for (int u = 0; u < NBX; ++u) {
            bool pred = qq[u] <= thr;                     // invalid qq -> false
            u64 bal = __ballot(pred);
            int slot = nv + __popcll(bal & lm);
            if (pred && slot < VCAP) {
                unsigned kv = crow[u * 64 + l];           // reload j (L1/L2-hot)
                sm.e.vlist[w][slot] = (unsigned short)(kv & 0xFFFFu);
            }
            nv += __popcll(bal);
        }
        nv = min(nv, VCAP);
        __syncthreads();
        float sqi = sq[row];
        const float* xi = x + (size_t)row * DIN;          // wave-uniform
#pragma unroll
        for (int r = 0; r < VCAP / 64; ++r) {
            int v = l + 64 * r;
            if (v < nv) {
                int j = (int)sm.e.vlist[w][v];
                const float4* bj = (const float4*)(x + (size_t)j * DIN);
                float s0 = 0.f, s1 = 0.f, s2 = 0.f, s3 = 0.f;
                float4 rb[8];                             // 2x8 stages: same
#pragma unroll
                for (int q = 0; q < 8; ++q) rb[q] = bj[q];
#pragma unroll
                for (int q = 0; q < 8; ++q) {             // FMA order per acc
                    s0 = fmaf(xi[4 * q + 0], rb[q].x, s0);//  chain == r1-r11
                    s1 = fmaf(xi[4 * q + 1], rb[q].y, s1);
                    s2 = fmaf(xi[4 * q + 2], rb[q].z, s2);
                    s3 = fmaf(xi[4 * q + 3], rb[q].w, s3);
                }
#pragma unroll
                for (int q = 0; q < 8; ++q) rb[q] = bj[8 + q];
#pragma unroll
                for (int q = 0; q < 8; ++q) {
                    s0 = fmaf(xi[32 + 4 * q + 0], rb[q].x, s0);
                    s1 = fmaf(xi[32 + 4 * q + 1], rb[q].y, s1);
                    s2 = fmaf(xi[32 + 4 * q + 2], rb[q].z, s2);
                    s3 = fmaf(xi[32 + 4 * q + 3], rb[q].w, s3);
                }
                float d = (s0 + s1) + (s2 + s3);
                float dist = fmaf(-2.0f, d, sqi + sq[j]);
                sm.e.ekeys[w][v] = ((u64)mono(dist) << 32) | (unsigned)j;
            }
        }
#pragma unroll
        for (int r = 0; r < VCAP / 64; ++r) {             // all-pairs rank
            int v = l + 64 * r;
            if (v < nv) {
                u64 mykey = sm.e.ekeys[w][v];
                int rank = 0;
                for (int i = 0; i < nv; ++i)
                    rank += (sm.e.ekeys[w][i] < mykey) ? 1 : 0;
                if (rank < KNN)
                    knn_s[w][rank] = (int)(unsigned)(mykey & 0xFFFFFFFFull);
            }
        }
    }
    __syncthreads();                                      // e.* dead after this
    // ---------------- phase A: agg + W2 GEMM ----------------
    {
        int o = t & 127, g = t >> 7;                      // g in {0,1}: 2 rows
        int row0 = blockIdx.x * 4;
#pragma unroll
        for (int r = 0; r < 2; ++r) {
            int rr = g * 2 + r;
            int i = row0 + rr;
            float u = U[(size_t)i * DOUT + o];
            float acc = 0.f;
#pragma unroll
            for (int q = 0; q < KNN; ++q)                 // same q-order as ref
                acc += fmaxf(u + V[(size_t)knn_s[rr][q] * DOUT + o], 0.0f);
            sm.a.ag[rr][o] = acc * (1.0f / KNN);
        }
        float a2[2] = {0.f, 0.f};
#pragma unroll
        for (int tile = 0; tile < 4; ++tile) {
            __syncthreads();
#pragma unroll
            for (int u = 0; u < 4; ++u)                   // 16 KB coalesced stage
                ((float4*)sm.a.w2t)[t + u * 256] =
                    ((const float4*)(W2 + tile * 32 * DOUT))[t + u * 256];
            __syncthreads();
#pragma unroll 8
            for (int kk = 0; kk < 32; ++kk) {
                float wv = sm.a.w2t[kk * DOUT + o];
#pragma unroll
                for (int r = 0; r < 2; ++r)
                    a2[r] = fmaf(sm.a.ag[g * 2 + r][tile * 32 + kk], wv, a2[r]);
            }
        }
        float bb = b2[o];
#pragma unroll
        for (int r = 0; r < 2; ++r)
            out[(size_t)(row0 + g * 2 + r) * DOUT + o] = a2[r] + bb;
    }
}

extern "C" void kernel_launch(void* const* d_in, const int* in_sizes, int n_in,
                              void* d_out, int out_size, void* d_ws, size_t ws_size,
                              hipStream_t stream) {
    const float* x  = (const float*)d_in[0];
    const float* W1 = (const float*)d_in[1];
    const float* b1 = (const float*)d_in[2];
    const float* W2 = (const float*)d_in[3];
    const float* b2 = (const float*)d_in[4];
    float* out = (float*)d_out;

    char* ws = (char*)d_ws;
    float*          sq      = (float*)(ws);                      // 32 KB
    float*          sqs     = (float*)(ws + 32768);              // 8 KB
    float*          tauf    = (float*)(ws + 40960);              // 32 KB
    unsigned short* Xs      = (unsigned short*)(ws + 73728);     // 256 KB
    unsigned short* Xh      = (unsigned short*)(ws + 655360);    // 1 MB
    float*          U       = (float*)(ws + 2097152);            // 4 MB
    float*          V       = (float*)(ws + 6291456);            // 4 MB
    unsigned*       cntpart = (unsigned*)(ws + 10485760);        // 512 KB
    unsigned*       cand    = (unsigned*)(ws + 11534336);        // 32 MB
    // total ws use ~45 MB (<< 268 MB workspace)

    k_pre<<<N / 8, 256, 0, stream>>>(x, W1, b1, sq, sqs, Xh, Xs, U, V);
    k_pretau<<<N / 16, 512, 0, stream>>>(Xh, Xs, sq, sqs, tauf);
    k_main<<<dim3(NBX, 128), 256, 0, stream>>>(Xh, sq, tauf, cand, cntpart);
    k_post<<<N / 4, 256, 0, stream>>>(x, sq, cntpart, cand, U, V, W2, b2, out);
}

// Round 9
// 172.967 us; speedup vs baseline: 1.1103x; 1.0196x over previous
//
#include <hip/hip_runtime.h>

#define N 8192
#define DIN 64
#define DOUT 128
#define KNN 16
#define MSAMP 2048         /* presample columns, stride 4 */
#define NBX 16             /* j-split in main scan (512 j per region) */
#define NST 8              /* stages per block: NST*64 = 512 j */
#define CAND_R 64          /* slots per (row, bx) region == wave width */
#define CAND_C (NBX * CAND_R)   /* 1024 per row */
#define EPS 1.0f           /* candidate-gate margin (passed r8-r11) */
#define DELTA_Q 64         /* verify-gate margin: 0.5 in dist units */
#define VCAP 128           /* verify-list capacity (expect ~45, >10 sigma) */

typedef unsigned long long u64;
typedef __attribute__((ext_vector_type(8))) short bf16x8;
typedef __attribute__((ext_vector_type(4))) float floatx4;

__device__ __forceinline__ unsigned mono(float f) {
    unsigned u = __float_as_uint(f);
    return (u & 0x80000000u) ? ~u : (u | 0x80000000u);
}
__device__ __forceinline__ unsigned short f2bf(float f) {   // RNE float->bf16
    unsigned u = __float_as_uint(f);
    return (unsigned short)((u + 0x7FFFu + ((u >> 16) & 1u)) >> 16);
}
__device__ __forceinline__ unsigned qdist(float dist) {     // round-up quant
    int q = (int)(dist * 128.0f) + 2;
    q = max(q, 0); return (unsigned)min(q, 65535);
}

// K1: fused pre (R8 geometry: 8 rows/block, 50% occ, 134 MB W1 replication).
__global__ __launch_bounds__(256, 4) void k_pre(const float* __restrict__ x,
                                                const float* __restrict__ W1,
                                                const float* __restrict__ b1,
                                                float* __restrict__ sq,
                                                float* __restrict__ sqs,
                                                unsigned short* __restrict__ Xh,
                                                unsigned short* __restrict__ Xs,
                                                float* __restrict__ U,
                                                float* __restrict__ V) {
    __shared__ float xs[8][DIN];
    int t = threadIdx.x;
    int r0 = blockIdx.x * 8;
    if (t < 128) {
        float4 xv = ((const float4*)x)[(size_t)r0 * (DIN / 4) + t];
        ((float4*)xs)[t] = xv;
        ushort4 h4;
        h4.x = f2bf(xv.x); h4.y = f2bf(xv.y);
        h4.z = f2bf(xv.z); h4.w = f2bf(xv.w);
        *(ushort4*)&Xh[r0 * DIN + t * 4] = h4;
    }
    __syncthreads();
    if (t < 32) {                                    // sampled rows r0, r0+4
        int s = t >> 4, c = t & 15;
        const float* xr = xs[s * 4];
        ushort4 h4;
        h4.x = f2bf(xr[c * 4 + 0]); h4.y = f2bf(xr[c * 4 + 1]);
        h4.z = f2bf(xr[c * 4 + 2]); h4.w = f2bf(xr[c * 4 + 3]);
        *(ushort4*)&Xs[(size_t)(2 * blockIdx.x + s) * DIN + c * 4] = h4;
    }
    if (t < 8) {
        const float4* xr = (const float4*)xs[t];
        float s0 = 0.f, s1 = 0.f, s2 = 0.f, s3 = 0.f;
#pragma unroll
        for (int q = 0; q < DIN / 4; ++q) {
            float4 a = xr[q];
            s0 = fmaf(a.x, a.x, s0); s1 = fmaf(a.y, a.y, s1);
            s2 = fmaf(a.z, a.z, s2); s3 = fmaf(a.w, a.w, s3);
        }
        float sv = (s0 + s1) + (s2 + s3);
        sq[r0 + t] = sv;
        if ((t & 3) == 0) sqs[(r0 + t) >> 2] = sv;   // sampled rows j = 4*scol
    }
    int o = t & 127, g = t >> 7;                     // g in {0,1}: rows g*4+u
    float aU[4], aV[4];
#pragma unroll
    for (int u = 0; u < 4; ++u) { aU[u] = 0.f; aV[u] = 0.f; }
    for (int kk = 0; kk < DIN; ++kk) {
        float whi = W1[kk * DOUT + o];
        float wlo = W1[(DIN + kk) * DOUT + o];
        float wd = whi - wlo;
#pragma unroll
        for (int u = 0; u < 4; ++u) {
            float xvv = xs[g * 4 + u][kk];
            aU[u] = fmaf(xvv, wd, aU[u]);
            aV[u] = fmaf(xvv, wlo, aV[u]);
        }
    }
    float bb = b1[o];
#pragma unroll
    for (int u = 0; u < 4; ++u) {
        int r = r0 + g * 4 + u;
        U[(size_t)r * DOUT + o] = aU[u] + bb;
        V[(size_t)r * DOUT + o] = aV[u];
    }
}

// K2: fused presample + tau, SALU-FREE radix (R8 post-mortem: the
// popcll(ballot) count = v_cmp -> s_bcnt1 -> s_add chains saturate the
// per-CU SHARED scalar unit: 16 waves x 64 ballots x 16 rounds ~ 36k SALU
// cyc/CU; wall was ~100k cyc/block at 24% VALUBusy).  New: 1024 thr =
// 16 waves, ONE row per wave, 32 values/lane; count via pure-VALU sign
// accumulation (neg += (v-c)>>31, 4 independent accumulators, no vcc/SALU)
// + one 6-step shfl_xor butterfly per round (LDS pipe).  Same per-row q
// multiset -> tau bit-identical.  ~45 VGPR + 64 KB LDS -> 2 blocks/CU.
__global__ __launch_bounds__(1024, 4) void k_pretau(const unsigned short* __restrict__ Xh,
                                                    const unsigned short* __restrict__ Xs,
                                                    const float* __restrict__ sq,
                                                    const float* __restrict__ sqs,
                                                    float* __restrict__ tauf) {
    __shared__ __align__(16) unsigned short qls[16 * MSAMP];   // 64 KB exactly
    int tid = threadIdx.x, w = tid >> 6, l = tid & 63;         // w in [0,16)
    int m = l & 15, quad = l >> 4, ko = quad * 8;
    int rt = blockIdx.x;
    int irow = rt * 16 + m;
    size_t arow = (size_t)irow * DIN;
    bf16x8 iH0 = *(const bf16x8*)(Xh + arow + ko);   // i-row frag (B)
    bf16x8 iH1 = *(const bf16x8*)(Xh + arow + 32 + ko);
    float si = sq[irow];
    int swz = (m & 7) << 4;
    for (int it = 0; it < 8; ++it) {                 // 16 waves x 8 tiles
        int s16 = w * 128 + it * 16;                 // scol tile base
        const unsigned short* sp = Xs + (size_t)(s16 + m) * DIN;  // dense rows
        bf16x8 sH0 = *(const bf16x8*)(sp + ko);      // sampled (A)
        bf16x8 sH1 = *(const bf16x8*)(sp + 32 + ko);
        floatx4 acc = {0.f, 0.f, 0.f, 0.f};
        acc = __builtin_amdgcn_mfma_f32_16x16x32_bf16(sH0, iH0, acc, 0, 0, 0);
        acc = __builtin_amdgcn_mfma_f32_16x16x32_bf16(sH1, iH1, acc, 0, 0, 0);
        int sc0 = s16 + quad * 4;                    // 4 consecutive scols
        float4 sj = *(const float4*)(sqs + sc0);
        unsigned q0 = qdist(fmaf(-2.0f, acc[0], si + sj.x));
        unsigned q1 = qdist(fmaf(-2.0f, acc[1], si + sj.y));
        unsigned q2 = qdist(fmaf(-2.0f, acc[2], si + sj.z));
        unsigned q3 = qdist(fmaf(-2.0f, acc[3], si + sj.w));
        u64 pk = (u64)q0 | ((u64)q1 << 16) | ((u64)q2 << 32) | ((u64)q3 << 48);
        *(u64*)&qls[m * MSAMP + (sc0 ^ swz)] = pk;   // multiset-preserving
    }
    __syncthreads();
    // wave w radix-selects row w; 32 values/lane, register-resident.
    const uint4* qv = (const uint4*)qls;             // 16B units
    unsigned v[32];
#pragma unroll
    for (int k = 0; k < 4; ++k) {
        uint4 t4 = qv[w * 256 + k * 64 + l];         // lane-contiguous 16B
        v[k*8+0] = t4.x & 0xFFFFu; v[k*8+1] = t4.x >> 16;
        v[k*8+2] = t4.y & 0xFFFFu; v[k*8+3] = t4.y >> 16;
        v[k*8+4] = t4.z & 0xFFFFu; v[k*8+5] = t4.z >> 16;
        v[k*8+6] = t4.w & 0xFFFFu; v[k*8+7] = t4.w >> 16;
    }
#pragma unroll
    for (int i = 0; i < 32; ++i)                     // pin in VGPRs
        asm volatile("" : "+v"(v[i]));
    unsigned p = 0;                                  // invariant: #{q < p} < 16
#pragma unroll
    for (int b = 15; b >= 0; --b) {
        unsigned c16 = p | (1u << b);
        int a0 = 0, a1 = 0, a2 = 0, a3 = 0;          // pure VALU, no SALU/vcc
#pragma unroll
        for (int i = 0; i < 8; ++i) {
            a0 += (int)(v[i]      - c16) >> 31;      // -1 iff v < c16
            a1 += (int)(v[8 + i]  - c16) >> 31;
            a2 += (int)(v[16 + i] - c16) >> 31;
            a3 += (int)(v[24 + i] - c16) >> 31;
        }
        int neg = (a0 + a1) + (a2 + a3);             // -(local count)
#pragma unroll
        for (int mk = 1; mk < 64; mk <<= 1)          // butterfly (LDS pipe)
            neg += __shfl_xor(neg, mk);
        if (-neg < 16) p = c16;                      // wave-uniform
    }
    if (l == 0) tauf[rt * 16 + w] = (float)p * (1.0f / 128.0f);
}

// K3: MFMA main scan (R4 geometry: NBX=16, 8 blocks/CU).
__global__ __launch_bounds__(256, 8) void k_main(const unsigned short* __restrict__ Xh,
                                                 const float* __restrict__ sq,
                                                 const float* __restrict__ tauf,
                                                 unsigned* __restrict__ cand,
                                                 unsigned* __restrict__ cntpart) {
    __shared__ __align__(16) short ldsH[64 * 72];
    int tid = threadIdx.x, w = tid >> 6, l = tid & 63;
    int m = l & 15, ko = (l >> 4) * 8;
    int bx = blockIdx.x;
    int rt = blockIdx.y * 4 + w;
    size_t arow = (size_t)(rt * 16 + m) * DIN;
    bf16x8 aH0 = *(const bf16x8*)(Xh + arow + ko);
    bf16x8 aH1 = *(const bf16x8*)(Xh + arow + 32 + ko);
    int rg[4]; float T[4]; float si[4]; int rowcnt[4];
#pragma unroll
    for (int reg = 0; reg < 4; ++reg) {
        rg[reg] = rt * 16 + (l >> 4) * 4 + reg;
        si[reg] = sq[rg[reg]];
        T[reg] = tauf[rg[reg]] + EPS - si[reg];
        rowcnt[reg] = 0;
    }
    int qs = l & 48;
    unsigned lmask = (1u << (l & 15)) - 1u;
    int srw = tid >> 3, scol8 = (tid & 7) * 8;

    for (int st = 0; st < NST; ++st) {
        int jbase = bx * (NST * 64) + st * 64;
        __syncthreads();
        *(bf16x8*)&ldsH[srw * 72 + scol8] =
            *(const bf16x8*)(Xh + (size_t)(jbase + srw) * DIN + scol8);
        *(bf16x8*)&ldsH[(srw + 32) * 72 + scol8] =
            *(const bf16x8*)(Xh + (size_t)(jbase + srw + 32) * DIN + scol8);
        __syncthreads();
#pragma unroll
        for (int it = 0; it < 4; ++it) {
            int br = it * 16 + m;
            bf16x8 bH0 = *(const bf16x8*)&ldsH[br * 72 + ko];
            bf16x8 bH1 = *(const bf16x8*)&ldsH[br * 72 + 32 + ko];
            floatx4 acc = {0.f, 0.f, 0.f, 0.f};
            acc = __builtin_amdgcn_mfma_f32_16x16x32_bf16(aH0, bH0, acc, 0, 0, 0);
            acc = __builtin_amdgcn_mfma_f32_16x16x32_bf16(aH1, bH1, acc, 0, 0, 0);
            int jcol = jbase + it * 16 + m;
            float sqj = sq[jcol];
#pragma unroll
            for (int reg = 0; reg < 4; ++reg) {
                float tv = fmaf(-2.0f, acc[reg], sqj);   // dist - si
                bool pass = tv <= T[reg];
                u64 bal = __ballot(pass);
                if (bal) {                               // skip empty
                    unsigned m16 = (unsigned)((bal >> qs) & 0xFFFFull);
                    if (pass) {
                        int slot = rowcnt[reg] + __popc(m16 & lmask);
                        if (slot < CAND_R)
                            cand[(size_t)rg[reg] * CAND_C + bx * CAND_R + slot] =
                                (qdist(tv + si[reg]) << 16) | (unsigned)jcol;
                    }
                    rowcnt[reg] += __popc(m16);
                }
            }
        }
    }
    if ((l & 15) == 0) {
#pragma unroll
        for (int reg = 0; reg < 4; ++reg)
            cntpart[rg[reg] * NBX + bx] = (unsigned)min(rowcnt[reg], CAND_R);
    }
}

// K4: fused [exact | aggout], compaction-free phase E (R5-verified).
__global__ __launch_bounds__(256, 8) void k_post(
    const float* __restrict__ x, const float* __restrict__ sq,
    const unsigned* __restrict__ cntpart, const unsigned* __restrict__ cand,
    const float* __restrict__ U, const float* __restrict__ V,
    const float* __restrict__ W2, const float* __restrict__ b2,
    float* __restrict__ out)
{
    __shared__ union {
        struct { unsigned short vlist[4][VCAP];           // 1 KB
                 u64 ekeys[4][VCAP]; } e;                 // 4 KB
        struct { float ag[4][DOUT];                       // 2 KB
                 float w2t[32 * DOUT]; } a;               // 16 KB
    } sm;
    __shared__ int knn_s[4][KNN];                         // survives both phases
    int t = threadIdx.x;
    int w = t >> 6, l = t & 63;
    int row = blockIdx.x * 4 + w;
    // ---------------- phase E: exact top-16 ----------------
    {
        unsigned c[NBX];
        const unsigned* cp = cntpart + (size_t)row * NBX; // wave-uniform -> s_load
#pragma unroll
        for (int b = 0; b < NBX; ++b) c[b] = min(cp[b], (unsigned)CAND_R);
        const unsigned* crow = cand + (size_t)row * CAND_C;
        unsigned qq[NBX];
#pragma unroll
        for (int u = 0; u < NBX; ++u) {                   // all loads independent
            unsigned kv = crow[u * 64 + l];               // coalesced 256B/reg
            qq[u] = ((unsigned)l < c[u]) ? (kv >> 16) : 0xFFFFFFFFu;
        }
        unsigned p = 0;                                   // radix-select q16
#pragma unroll
        for (int b = 15; b >= 0; --b) {
            unsigned c16 = p | (1u << b);
            int cnt = 0;
#pragma unroll
            for (int u = 0; u < NBX; ++u)
                cnt += __popcll(__ballot(qq[u] < c16));
            if (cnt < 16) p = c16;
        }
        unsigned thr = p + DELTA_Q;                       // verify gate on q
        int nv = 0;
        u64 lm = (l == 63) ? 0xFFFFFFFFFFFFFFFFull >> 1 : (1ull << l) - 1ull;
#pragma unroll
        for (int u = 0; u < NBX; ++u) {
            bool pred = qq[u] <= thr;                     // invalid qq -> false
            u64 bal = __ballot(pred);
            int slot = nv + __popcll(bal & lm);
            if (pred && slot < VCAP) {
                unsigned kv = crow[u * 64 + l];           // reload j (L1/L2-hot)
                sm.e.vlist[w][slot] = (unsigned short)(kv & 0xFFFFu);
            }
            nv += __popcll(bal);
        }
        nv = min(nv, VCAP);
        __syncthreads();
        float sqi = sq[row];
        const float* xi = x + (size_t)row * DIN;          // wave-uniform
#pragma unroll
        for (int r = 0; r < VCAP / 64; ++r) {
            int v = l + 64 * r;
            if (v < nv) {
                int j = (int)sm.e.vlist[w][v];
                const float4* bj = (const float4*)(x + (size_t)j * DIN);
                float s0 = 0.f, s1 = 0.f, s2 = 0.f, s3 = 0.f;
                float4 rb[8];                             // 2x8 stages: same
#pragma unroll
                for (int q = 0; q < 8; ++q) rb[q] = bj[q];
#pragma unroll
                for (int q = 0; q < 8; ++q) {             // FMA order per acc
                    s0 = fmaf(xi[4 * q + 0], rb[q].x, s0);//  chain == r1-r11
                    s1 = fmaf(xi[4 * q + 1], rb[q].y, s1);
                    s2 = fmaf(xi[4 * q + 2], rb[q].z, s2);
                    s3 = fmaf(xi[4 * q + 3], rb[q].w, s3);
                }
#pragma unroll
                for (int q = 0; q < 8; ++q) rb[q] = bj[8 + q];
#pragma unroll
                for (int q = 0; q < 8; ++q) {
                    s0 = fmaf(xi[32 + 4 * q + 0], rb[q].x, s0);
                    s1 = fmaf(xi[32 + 4 * q + 1], rb[q].y, s1);
                    s2 = fmaf(xi[32 + 4 * q + 2], rb[q].z, s2);
                    s3 = fmaf(xi[32 + 4 * q + 3], rb[q].w, s3);
                }
                float d = (s0 + s1) + (s2 + s3);
                float dist = fmaf(-2.0f, d, sqi + sq[j]);
                sm.e.ekeys[w][v] = ((u64)mono(dist) << 32) | (unsigned)j;
            }
        }
#pragma unroll
        for (int r = 0; r < VCAP / 64; ++r) {             // all-pairs rank
            int v = l + 64 * r;
            if (v < nv) {
                u64 mykey = sm.e.ekeys[w][v];
                int rank = 0;
                for (int i = 0; i < nv; ++i)
                    rank += (sm.e.ekeys[w][i] < mykey) ? 1 : 0;
                if (rank < KNN)
                    knn_s[w][rank] = (int)(unsigned)(mykey & 0xFFFFFFFFull);
            }
        }
    }
    __syncthreads();                                      // e.* dead after this
    // ---------------- phase A: agg + W2 GEMM ----------------
    {
        int o = t & 127, g = t >> 7;                      // g in {0,1}: 2 rows
        int row0 = blockIdx.x * 4;
#pragma unroll
        for (int r = 0; r < 2; ++r) {
            int rr = g * 2 + r;
            int i = row0 + rr;
            float u = U[(size_t)i * DOUT + o];
            float acc = 0.f;
#pragma unroll
            for (int q = 0; q < KNN; ++q)                 // same q-order as ref
                acc += fmaxf(u + V[(size_t)knn_s[rr][q] * DOUT + o], 0.0f);
            sm.a.ag[rr][o] = acc * (1.0f / KNN);
        }
        float a2[2] = {0.f, 0.f};
#pragma unroll
        for (int tile = 0; tile < 4; ++tile) {
            __syncthreads();
#pragma unroll
            for (int u = 0; u < 4; ++u)                   // 16 KB coalesced stage
                ((float4*)sm.a.w2t)[t + u * 256] =
                    ((const float4*)(W2 + tile * 32 * DOUT))[t + u * 256];
            __syncthreads();
#pragma unroll 8
            for (int kk = 0; kk < 32; ++kk) {
                float wv = sm.a.w2t[kk * DOUT + o];
#pragma unroll
                for (int r = 0; r < 2; ++r)
                    a2[r] = fmaf(sm.a.ag[g * 2 + r][tile * 32 + kk], wv, a2[r]);
            }
        }
        float bb = b2[o];
#pragma unroll
        for (int r = 0; r < 2; ++r)
            out[(size_t)(row0 + g * 2 + r) * DOUT + o] = a2[r] + bb;
    }
}

extern "C" void kernel_launch(void* const* d_in, const int* in_sizes, int n_in,
                              void* d_out, int out_size, void* d_ws, size_t ws_size,
                              hipStream_t stream) {
    const float* x  = (const float*)d_in[0];
    const float* W1 = (const float*)d_in[1];
    const float* b1 = (const float*)d_in[2];
    const float* W2 = (const float*)d_in[3];
    const float* b2 = (const float*)d_in[4];
    float* out = (float*)d_out;

    char* ws = (char*)d_ws;
    float*          sq      = (float*)(ws);                      // 32 KB
    float*          sqs     = (float*)(ws + 32768);              // 8 KB
    float*          tauf    = (float*)(ws + 40960);              // 32 KB
    unsigned short* Xs      = (unsigned short*)(ws + 73728);     // 256 KB
    unsigned short* Xh      = (unsigned short*)(ws + 655360);    // 1 MB
    float*          U       = (float*)(ws + 2097152);            // 4 MB
    float*          V       = (float*)(ws + 6291456);            // 4 MB
    unsigned*       cntpart = (unsigned*)(ws + 10485760);        // 512 KB
    unsigned*       cand    = (unsigned*)(ws + 11534336);        // 32 MB
    // total ws use ~45 MB (<< 268 MB workspace)

    k_pre<<<N / 8, 256, 0, stream>>>(x, W1, b1, sq, sqs, Xh, Xs, U, V);
    k_pretau<<<N / 16, 1024, 0, stream>>>(Xh, Xs, sq, sqs, tauf);
    k_main<<<dim3(NBX, 128), 256, 0, stream>>>(Xh, sq, tauf, cand, cntpart);
    k_post<<<N / 4, 256, 0, stream>>>(x, sq, cntpart, cand, U, V, W2, b2, out);
}